// Round 1
// baseline (593.384 us; speedup 1.0000x reference)
//
#include <hip/hip_runtime.h>

// GraphUpSample: out[b,o,f,n*2+k] = sum_c x[b,c,f,n]*W[n,c,o,k] + bias[n,o]
// B=32 C_IN=512 F=128 N=16 C_OUT=512 K=2
// Pipeline (primary, needs 208 MB ws):
//   1a: x[b,c,f,n] f32 -> xT[n][m=b*128+f][c] bf16      (67 MB)
//   1b: W[n,c,o,k] f32 -> WbT[n][j=o*2+k][c] bf16       (16.7 MB)
//   2 : per-node GEMM (m97-style 128x128 MFMA bf16) -> Y[n][m][j] bf16 (+bias) (128 MB)
//   3 : LDS transpose reassembly Y -> out[b][o][f][nk] f32
// Fallback (ws too small): direct fp32 tiled GEMM, correct but slow.

typedef unsigned short u16;
typedef unsigned int u32;
typedef __attribute__((ext_vector_type(8))) u16 u16x8;
typedef __attribute__((ext_vector_type(8))) __bf16 bf16x8;
typedef __attribute__((ext_vector_type(4))) float f32x4;

typedef const __attribute__((address_space(1))) void* gas_p;
typedef __attribute__((address_space(3))) void* las_p;

__device__ __forceinline__ u16 f2bf(float f) {
    u32 u = __float_as_uint(f);
    u += 0x7fffu + ((u >> 16) & 1u);   // RTNE
    return (u16)(u >> 16);
}
__device__ __forceinline__ float bf2f(u32 lo16) {
    return __uint_as_float(lo16 << 16);
}
__device__ __forceinline__ void g2l16(const void* g, void* l) {
    // async global->LDS, 16B per lane; LDS dest = wave-uniform base + lane*16
    __builtin_amdgcn_global_load_lds((gas_p)g, (las_p)l, 16, 0, 0);
}

// ---------------- Pass 1a: x -> xT[n][m][c] bf16 ----------------
// grid 2048 (= b32 * ftile8 * ctile8), block 256.
// Reads: fully coalesced 1KB/instr along (f,n). Writes: 16B runs along c.
__global__ __launch_bounds__(256) void k_transpose_x(const float* __restrict__ x,
                                                     u16* __restrict__ xT) {
    int bid = blockIdx.x;
    int ct  = bid & 7;          // c-tile (64 c each)
    int ftl = (bid >> 3) & 7;   // f-tile (16 f each)
    int b   = bid >> 6;
    int c0 = ct * 64, f0 = ftl * 16;
    int t = threadIdx.x;
    int fi = t >> 4, n = t & 15;            // t == fi*16 + n == (f-f0)*16 + n
    const float* xb = x + (size_t)b * 1048576 + (size_t)f0 * 16 + t;
    u16* dst = xT + ((size_t)n * 4096 + b * 128 + f0 + fi) * 512 + c0;
#pragma unroll
    for (int c8 = 0; c8 < 8; ++c8) {
        u16x8 v;
#pragma unroll
        for (int e = 0; e < 8; ++e)
            v[e] = f2bf(xb[(size_t)(c0 + c8 * 8 + e) * 2048]);
        *(u16x8*)&dst[c8 * 8] = v;
    }
}

// ---------------- Pass 1b: W -> WbT[n][j][c] bf16 ----------------
// grid 4096, block 256. Reads coalesced along j; 16B writes along c.
__global__ __launch_bounds__(256) void k_transpose_w(const float* __restrict__ W,
                                                     u16* __restrict__ WbT) {
    int v = blockIdx.x * 256 + threadIdx.x;   // 1,048,576 works
    int j  = v & 1023;
    int c8 = (v >> 10) & 63;
    int n  = v >> 16;
    const float* src = W + (size_t)n * 524288 + (size_t)c8 * 8192 + j;
    u16x8 o;
#pragma unroll
    for (int e = 0; e < 8; ++e)
        o[e] = f2bf(src[(size_t)e * 1024]);
    *(u16x8*)&WbT[((size_t)n * 1024 + j) * 512 + c8 * 8] = o;
}

// ---------------- Pass 2: batched GEMM -> Y[n][m][j] bf16 ----------------
// m97 structure: 128x128 tile, BK=32, 4 waves (2x2), 16x16x32 bf16 MFMA,
// global_load_lds width 16, single-buffered LDS, 2 barriers/K-step.
__global__ __launch_bounds__(256) void k_gemm(const u16* __restrict__ xT,
                                              const u16* __restrict__ WbT,
                                              const float* __restrict__ bias,
                                              u16* __restrict__ Y) {
    int bid = blockIdx.x;
    int jt = bid & 7;            // 8 j-tiles of 128
    int mt = (bid >> 3) & 31;    // 32 m-tiles of 128
    int n  = bid >> 8;           // 16 nodes
    int m0 = mt * 128, j0 = jt * 128;
    int t = threadIdx.x;
    int w = t >> 6, l = t & 63;
    int wr = w >> 1, wc = w & 1;                 // 2x2 wave grid; wave tile 64x64

    __shared__ __align__(16) u16 As[128][32];    // [m][c] bf16
    __shared__ __align__(16) u16 Bs[128][32];    // [j][c] bf16

    const u16* An = xT  + ((size_t)n * 4096 + m0) * 512;
    const u16* Bn = WbT + ((size_t)n * 1024 + j0) * 512;

    int row_a = t >> 2;            // 0..63 (i adds 64)
    int coff  = (t & 3) * 8;       // element offset within BK=32
    char* AsB = (char*)&As[0][0];
    char* BsB = (char*)&Bs[0][0];

    f32x4 acc[4][4] = {};

    for (int kt = 0; kt < 16; ++kt) {
        int c0 = kt * 32;
        // stage A (128x32) and B (128x32), 16B/lane, 2 instrs each
        g2l16(&An[(size_t)row_a * 512 + c0 + coff],        AsB + t * 16);
        g2l16(&An[(size_t)(row_a + 64) * 512 + c0 + coff], AsB + 4096 + t * 16);
        g2l16(&Bn[(size_t)row_a * 512 + c0 + coff],        BsB + t * 16);
        g2l16(&Bn[(size_t)(row_a + 64) * 512 + c0 + coff], BsB + 4096 + t * 16);
        asm volatile("s_waitcnt vmcnt(0)" ::: "memory");
        __syncthreads();

        bf16x8 a[4], bb[4];
#pragma unroll
        for (int mi = 0; mi < 4; ++mi)
            a[mi] = *(const bf16x8*)&As[wr * 64 + mi * 16 + (l & 15)][(l >> 4) * 8];
#pragma unroll
        for (int ji = 0; ji < 4; ++ji)
            bb[ji] = *(const bf16x8*)&Bs[wc * 64 + ji * 16 + (l & 15)][(l >> 4) * 8];
#pragma unroll
        for (int mi = 0; mi < 4; ++mi)
#pragma unroll
            for (int ji = 0; ji < 4; ++ji)
                acc[mi][ji] = __builtin_amdgcn_mfma_f32_16x16x32_bf16(
                    a[mi], bb[ji], acc[mi][ji], 0, 0, 0);
        __syncthreads();
    }

    // epilogue: D mapping col=lane&15, row=(lane>>4)*4+r  [HW-verified]
    float bv[4];
#pragma unroll
    for (int ji = 0; ji < 4; ++ji) {
        int j = j0 + wc * 64 + ji * 16 + (l & 15);
        bv[ji] = bias[n * 512 + (j >> 1)];
    }
    u16* Yn = Y + (size_t)n * 4194304;
#pragma unroll
    for (int mi = 0; mi < 4; ++mi) {
        int rbase = m0 + wr * 64 + mi * 16 + (l >> 4) * 4;
#pragma unroll
        for (int r = 0; r < 4; ++r) {
            int m = rbase + r;
#pragma unroll
            for (int ji = 0; ji < 4; ++ji) {
                int j = j0 + wc * 64 + ji * 16 + (l & 15);
                Yn[(size_t)m * 1024 + j] = f2bf(acc[mi][ji][r] + bv[ji]);
            }
        }
    }
}

// ---------------- Pass 3: Y[n][m][j] bf16 -> out[b][o][f][nk] f32 ----------------
// grid 8192 (= b32 * otile32 * ftile8), block 256. Full-64B reads (32 j per (n,f)),
// float4 coalesced writes. LDS pitches (80B/f-row, 1296B/n-plane) keep reads ~2-way.
__global__ __launch_bounds__(256) void k_reassemble(const u16* __restrict__ Y,
                                                    float* __restrict__ out) {
    int bid = blockIdx.x;
    int ft = bid & 7;            // 8 f-tiles of 16
    int ot = (bid >> 3) & 31;    // 32 o-tiles of 16
    int b  = bid >> 8;
    int f0 = ft * 16, o0 = ot * 16;
    int t = threadIdx.x;

    __shared__ __align__(16) unsigned char st[16 * 1296]; // [n]:1296B, [f]:80B, [j]:2B
    {
        int n = t >> 4, fi = t & 15;
        const u16* src = Y + ((size_t)n * 4096 + b * 128 + f0 + fi) * 1024 + o0 * 2;
        u16x8* dst = (u16x8*)&st[n * 1296 + fi * 80];
        const u16x8* s8 = (const u16x8*)src;
        dst[0] = s8[0]; dst[1] = s8[1]; dst[2] = s8[2]; dst[3] = s8[3];
    }
    __syncthreads();

    float* ob = out + (size_t)b * 2097152 + (size_t)o0 * 4096 + (size_t)f0 * 32;
#pragma unroll
    for (int i = 0; i < 8; ++i) {
        int w4  = i * 256 + t;        // 2048 float4 per block
        int o_l = w4 >> 7;            // 0..15
        int fi  = (w4 >> 3) & 15;
        int nk4 = w4 & 7;             // float4 covers nk = nk4*4 .. +3
        int n0  = nk4 * 2;
        u32 p0 = *(const u32*)&st[n0 * 1296 + fi * 80 + o_l * 4];
        u32 p1 = *(const u32*)&st[(n0 + 1) * 1296 + fi * 80 + o_l * 4];
        float4 v;
        v.x = bf2f(p0 & 0xffffu); v.y = bf2f(p0 >> 16);
        v.z = bf2f(p1 & 0xffffu); v.w = bf2f(p1 >> 16);
        *(float4*)&ob[(size_t)o_l * 4096 + fi * 32 + nk4 * 4] = v;
    }
}

// ---------------- Fallback: direct fp32 tiled GEMM (no workspace) ----------------
// grid 16384 (= n16 * mt64 * jt16), block 256; 64x64 tile, BK=16.
__global__ __launch_bounds__(256) void k_fallback(const float* __restrict__ x,
                                                  const float* __restrict__ W,
                                                  const float* __restrict__ bias,
                                                  float* __restrict__ out) {
    int bid = blockIdx.x;
    int jt = bid & 15;
    int mt = (bid >> 4) & 63;
    int n  = bid >> 10;
    int m0 = mt * 64;
    int b  = m0 >> 7;
    int f0 = m0 & 127;
    int j0 = jt * 64;
    int t = threadIdx.x;
    int tr = t >> 4, tc = t & 15;
    __shared__ float xs[16][65];
    __shared__ float wt[16][65];
    float acc[4][4] = {};
    const float* xb = x + (size_t)b * 1048576 + (size_t)f0 * 16 + n;
    const float* Wn = W + (size_t)n * 524288 + j0;
    for (int c0 = 0; c0 < 512; c0 += 16) {
#pragma unroll
        for (int i = 0; i < 4; ++i) {
            int v  = i * 256 + t;
            int ci = v >> 6, e = v & 63;
            xs[ci][e] = xb[(size_t)(c0 + ci) * 2048 + (size_t)e * 16];
            wt[ci][e] = Wn[(size_t)(c0 + ci) * 1024 + e];
        }
        __syncthreads();
#pragma unroll
        for (int c = 0; c < 16; ++c) {
            float a0 = xs[c][tr * 4], a1 = xs[c][tr * 4 + 1],
                  a2 = xs[c][tr * 4 + 2], a3 = xs[c][tr * 4 + 3];
            float w0 = wt[c][tc * 4], w1 = wt[c][tc * 4 + 1],
                  w2 = wt[c][tc * 4 + 2], w3 = wt[c][tc * 4 + 3];
            acc[0][0] = fmaf(a0, w0, acc[0][0]); acc[0][1] = fmaf(a0, w1, acc[0][1]);
            acc[0][2] = fmaf(a0, w2, acc[0][2]); acc[0][3] = fmaf(a0, w3, acc[0][3]);
            acc[1][0] = fmaf(a1, w0, acc[1][0]); acc[1][1] = fmaf(a1, w1, acc[1][1]);
            acc[1][2] = fmaf(a1, w2, acc[1][2]); acc[1][3] = fmaf(a1, w3, acc[1][3]);
            acc[2][0] = fmaf(a2, w0, acc[2][0]); acc[2][1] = fmaf(a2, w1, acc[2][1]);
            acc[2][2] = fmaf(a2, w2, acc[2][2]); acc[2][3] = fmaf(a2, w3, acc[2][3]);
            acc[3][0] = fmaf(a3, w0, acc[3][0]); acc[3][1] = fmaf(a3, w1, acc[3][1]);
            acc[3][2] = fmaf(a3, w2, acc[3][2]); acc[3][3] = fmaf(a3, w3, acc[3][3]);
        }
        __syncthreads();
    }
#pragma unroll
    for (int r = 0; r < 4; ++r) {
        int f = f0 + tr * 4 + r;
#pragma unroll
        for (int q = 0; q < 4; ++q) {
            int j = j0 + tc * 4 + q;
            int o = j >> 1, k = j & 1;
            out[(size_t)b * 2097152 + (size_t)o * 4096 + (size_t)f * 32 + n * 2 + k] =
                acc[r][q] + bias[n * 512 + o];
        }
    }
}

extern "C" void kernel_launch(void* const* d_in, const int* in_sizes, int n_in,
                              void* d_out, int out_size, void* d_ws, size_t ws_size,
                              hipStream_t stream) {
    (void)in_sizes; (void)n_in; (void)out_size;
    const float* x    = (const float*)d_in[0];
    const float* W    = (const float*)d_in[1];
    const float* bias = (const float*)d_in[2];
    float* out = (float*)d_out;

    const size_t xT_bytes = 67108864;    // 16*4096*512 bf16
    const size_t Wb_bytes = 16777216;    // 16*1024*512 bf16
    const size_t Y_bytes  = 134217728;   // 16*4096*1024 bf16
    const size_t need = xT_bytes + Wb_bytes + Y_bytes;   // 208 MB

    if (ws_size >= need) {
        u16* xT  = (u16*)d_ws;
        u16* WbT = (u16*)((char*)d_ws + xT_bytes);
        u16* Y   = (u16*)((char*)d_ws + xT_bytes + Wb_bytes);
        k_transpose_x<<<dim3(2048), dim3(256), 0, stream>>>(x, xT);
        k_transpose_w<<<dim3(4096), dim3(256), 0, stream>>>(W, WbT);
        k_gemm<<<dim3(4096), dim3(256), 0, stream>>>(xT, WbT, bias, Y);
        k_reassemble<<<dim3(8192), dim3(256), 0, stream>>>(Y, out);
    } else {
        k_fallback<<<dim3(16384), dim3(256), 0, stream>>>(x, W, bias, out);
    }
}

// Round 2
// 520.802 us; speedup vs baseline: 1.1394x; 1.1394x over previous
//
#include <hip/hip_runtime.h>

// GraphUpSample: out[b,o,f,n*2+k] = sum_c x[b,c,f,n]*W[n,c,o,k] + bias[n,o]
// B=32 C_IN=512 F=128 N=16 C_OUT=512 K=2
// Pipeline (primary, needs 208 MB ws):
//   1a: x[b,c,f,n] f32 -> xT[n][m=b*128+f][c] bf16      (67 MB)  [LDS-coalesced stores]
//   1b: W[n,c,o,k] f32 -> WbT[n][j=o*2+k][c] bf16       (16.7 MB)[LDS-coalesced stores]
//   2 : per-node GEMM (m97-style 128x128 MFMA bf16) -> Y[n][m][j] bf16 (+bias)
//       with XCD-aware swizzle: xcd p&7 owns nodes {p&7, (p&7)+8}; jt fastest
//       so the 8 j-tiles sharing an A-tile colocate on one XCD's L2.
//   3 : LDS transpose reassembly Y -> out[b][o][f][nk] f32
// Fallback (ws too small): direct fp32 tiled GEMM, correct but slow.

typedef unsigned short u16;
typedef unsigned int u32;
typedef __attribute__((ext_vector_type(8))) u16 u16x8;
typedef __attribute__((ext_vector_type(8))) __bf16 bf16x8;
typedef __attribute__((ext_vector_type(4))) float f32x4;

typedef const __attribute__((address_space(1))) void* gas_p;
typedef __attribute__((address_space(3))) void* las_p;

__device__ __forceinline__ u16 f2bf(float f) {
    u32 u = __float_as_uint(f);
    u += 0x7fffu + ((u >> 16) & 1u);   // RTNE
    return (u16)(u >> 16);
}
__device__ __forceinline__ float bf2f(u32 lo16) {
    return __uint_as_float(lo16 << 16);
}
__device__ __forceinline__ void g2l16(const void* g, void* l) {
    __builtin_amdgcn_global_load_lds((gas_p)g, (las_p)l, 16, 0, 0);
}

// ---------------- Pass 1a: x -> xT[n][m][c] bf16 ----------------
// grid 2048 (= b32 * ftile8 * ctile8), block 256.
// Reads: coalesced 1KB/instr along (f,n). LDS transpose (XOR-swizzled, b128-floor
// banking) then cooperative stores as 128B runs (full-line writes, no amplification).
__global__ __launch_bounds__(256) void k_transpose_x(const float* __restrict__ x,
                                                     u16* __restrict__ xT) {
    int bid = blockIdx.x;
    int ct  = bid & 7;          // c-tile (64 c each)
    int ftl = (bid >> 3) & 7;   // f-tile (16 f each)
    int b   = bid >> 6;
    int c0 = ct * 64, f0 = ftl * 16;
    int t = threadIdx.x;        // fn offset within tile: fi = t>>4, n = t&15
    const float* xb = x + (size_t)b * 1048576 + (size_t)c0 * 2048 + f0 * 16 + t;

    __shared__ __align__(16) u16x8 st[256][8];   // [fn][chunk], chunk swizzled ^ (fn&7)

#pragma unroll
    for (int c8 = 0; c8 < 8; ++c8) {
        u16x8 v;
#pragma unroll
        for (int e = 0; e < 8; ++e)
            v[e] = f2bf(xb[(size_t)(c8 * 8 + e) * 2048]);
        st[t][c8 ^ (t & 7)] = v;
    }
    __syncthreads();
    // cooperative write: lanes 0..7 cover the 8 chunks of one row -> 128B contiguous
#pragma unroll
    for (int it = 0; it < 8; ++it) {
        int rr = it * 32 + (t >> 3);             // row (fn) 0..255
        int ch = t & 7;
        u16x8 v = st[rr][ch ^ (rr & 7)];
        u16* dst = xT + ((size_t)(rr & 15) * 4096 + b * 128 + f0 + (rr >> 4)) * 512
                      + c0 + ch * 8;
        *(u16x8*)dst = v;
    }
}

// ---------------- Pass 1b: W -> WbT[n][j][c] bf16 ----------------
// grid 512 (= n16 * jtile4 * ctile8), block 256. Same LDS-coalesce structure.
__global__ __launch_bounds__(256) void k_transpose_w(const float* __restrict__ W,
                                                     u16* __restrict__ WbT) {
    int bid = blockIdx.x;
    int ct = bid & 7;           // c-tile (64 c)
    int jt = (bid >> 3) & 3;    // j-tile (256 j)
    int n  = bid >> 5;
    int c0 = ct * 64, j0 = jt * 256;
    int t = threadIdx.x;        // j-local
    const float* src = W + (size_t)n * 524288 + (size_t)c0 * 1024 + j0 + t;

    __shared__ __align__(16) u16x8 st[256][8];

#pragma unroll
    for (int c8 = 0; c8 < 8; ++c8) {
        u16x8 v;
#pragma unroll
        for (int e = 0; e < 8; ++e)
            v[e] = f2bf(src[(size_t)(c8 * 8 + e) * 1024]);
        st[t][c8 ^ (t & 7)] = v;
    }
    __syncthreads();
#pragma unroll
    for (int it = 0; it < 8; ++it) {
        int rr = it * 32 + (t >> 3);             // j-local row
        int ch = t & 7;
        u16x8 v = st[rr][ch ^ (rr & 7)];
        *(u16x8*)&WbT[((size_t)n * 1024 + j0 + rr) * 512 + c0 + ch * 8] = v;
    }
}

// ---------------- Pass 2: batched GEMM -> Y[n][m][j] bf16 ----------------
// m97 structure: 128x128 tile, BK=32, 4 waves (2x2), 16x16x32 bf16 MFMA,
// global_load_lds width 16, single-buffered LDS, 2 barriers/K-step.
// XCD swizzle (assumes physical XCD = blockIdx%8): XCD x runs nodes {x, x+8};
// within XCD: jt fastest (A-tile L2 reuse), then mt, then node.
__global__ __launch_bounds__(256) void k_gemm(const u16* __restrict__ xT,
                                              const u16* __restrict__ WbT,
                                              const float* __restrict__ bias,
                                              u16* __restrict__ Y) {
    int p = blockIdx.x;
    int xcd = p & 7;
    int s   = p >> 3;            // 0..511 slot on this XCD
    int jt  = s & 7;             // 8 j-tiles of 128
    int mt  = (s >> 3) & 31;     // 32 m-tiles of 128
    int n   = xcd + ((s >> 8) << 3);   // nodes {xcd, xcd+8}
    int m0 = mt * 128, j0 = jt * 128;
    int t = threadIdx.x;
    int w = t >> 6, l = t & 63;
    int wr = w >> 1, wc = w & 1;                 // 2x2 wave grid; wave tile 64x64

    __shared__ __align__(16) u16 As[128][32];    // [m][c] bf16
    __shared__ __align__(16) u16 Bs[128][32];    // [j][c] bf16

    const u16* An = xT  + ((size_t)n * 4096 + m0) * 512;
    const u16* Bn = WbT + ((size_t)n * 1024 + j0) * 512;

    int row_a = t >> 2;            // 0..63 (second half adds 64)
    int coff  = (t & 3) * 8;       // element offset within BK=32
    char* AsB = (char*)&As[0][0];
    char* BsB = (char*)&Bs[0][0];

    f32x4 acc[4][4] = {};

    for (int kt = 0; kt < 16; ++kt) {
        int c0 = kt * 32;
        g2l16(&An[(size_t)row_a * 512 + c0 + coff],        AsB + t * 16);
        g2l16(&An[(size_t)(row_a + 64) * 512 + c0 + coff], AsB + 4096 + t * 16);
        g2l16(&Bn[(size_t)row_a * 512 + c0 + coff],        BsB + t * 16);
        g2l16(&Bn[(size_t)(row_a + 64) * 512 + c0 + coff], BsB + 4096 + t * 16);
        asm volatile("s_waitcnt vmcnt(0)" ::: "memory");
        __syncthreads();

        bf16x8 a[4], bb[4];
#pragma unroll
        for (int mi = 0; mi < 4; ++mi)
            a[mi] = *(const bf16x8*)&As[wr * 64 + mi * 16 + (l & 15)][(l >> 4) * 8];
#pragma unroll
        for (int ji = 0; ji < 4; ++ji)
            bb[ji] = *(const bf16x8*)&Bs[wc * 64 + ji * 16 + (l & 15)][(l >> 4) * 8];
#pragma unroll
        for (int mi = 0; mi < 4; ++mi)
#pragma unroll
            for (int ji = 0; ji < 4; ++ji)
                acc[mi][ji] = __builtin_amdgcn_mfma_f32_16x16x32_bf16(
                    a[mi], bb[ji], acc[mi][ji], 0, 0, 0);
        __syncthreads();
    }

    // epilogue: D mapping col=lane&15, row=(lane>>4)*4+r  [HW-verified]
    float bv[4];
#pragma unroll
    for (int ji = 0; ji < 4; ++ji) {
        int j = j0 + wc * 64 + ji * 16 + (l & 15);
        bv[ji] = bias[n * 512 + (j >> 1)];
    }
    u16* Yn = Y + (size_t)n * 4194304;
#pragma unroll
    for (int mi = 0; mi < 4; ++mi) {
        int rbase = m0 + wr * 64 + mi * 16 + (l >> 4) * 4;
#pragma unroll
        for (int r = 0; r < 4; ++r) {
            int m = rbase + r;
#pragma unroll
            for (int ji = 0; ji < 4; ++ji) {
                int j = j0 + wc * 64 + ji * 16 + (l & 15);
                Yn[(size_t)m * 1024 + j] = f2bf(acc[mi][ji][r] + bv[ji]);
            }
        }
    }
}

// ---------------- Pass 3: Y[n][m][j] bf16 -> out[b][o][f][nk] f32 ----------------
// grid 8192 (= b32 * otile32 * ftile8), block 256. 64B-contiguous reads per thread,
// float4 coalesced writes.
__global__ __launch_bounds__(256) void k_reassemble(const u16* __restrict__ Y,
                                                    float* __restrict__ out) {
    int bid = blockIdx.x;
    int ft = bid & 7;            // 8 f-tiles of 16
    int ot = (bid >> 3) & 31;    // 32 o-tiles of 16
    int b  = bid >> 8;
    int f0 = ft * 16, o0 = ot * 16;
    int t = threadIdx.x;

    __shared__ __align__(16) unsigned char st[16 * 1296]; // [n]:1296B, [f]:80B, [j]:2B
    {
        int n = t >> 4, fi = t & 15;
        const u16* src = Y + ((size_t)n * 4096 + b * 128 + f0 + fi) * 1024 + o0 * 2;
        u16x8* dst = (u16x8*)&st[n * 1296 + fi * 80];
        const u16x8* s8 = (const u16x8*)src;
        dst[0] = s8[0]; dst[1] = s8[1]; dst[2] = s8[2]; dst[3] = s8[3];
    }
    __syncthreads();

    float* ob = out + (size_t)b * 2097152 + (size_t)o0 * 4096 + (size_t)f0 * 32;
#pragma unroll
    for (int i = 0; i < 8; ++i) {
        int w4  = i * 256 + t;        // 2048 float4 per block
        int o_l = w4 >> 7;            // 0..15
        int fi  = (w4 >> 3) & 15;
        int nk4 = w4 & 7;             // float4 covers nk = nk4*4 .. +3
        int n0  = nk4 * 2;
        u32 p0 = *(const u32*)&st[n0 * 1296 + fi * 80 + o_l * 4];
        u32 p1 = *(const u32*)&st[(n0 + 1) * 1296 + fi * 80 + o_l * 4];
        float4 v;
        v.x = bf2f(p0 & 0xffffu); v.y = bf2f(p0 >> 16);
        v.z = bf2f(p1 & 0xffffu); v.w = bf2f(p1 >> 16);
        *(float4*)&ob[(size_t)o_l * 4096 + fi * 32 + nk4 * 4] = v;
    }
}

// ---------------- Fallback: direct fp32 tiled GEMM (no workspace) ----------------
__global__ __launch_bounds__(256) void k_fallback(const float* __restrict__ x,
                                                  const float* __restrict__ W,
                                                  const float* __restrict__ bias,
                                                  float* __restrict__ out) {
    int bid = blockIdx.x;
    int jt = bid & 15;
    int mt = (bid >> 4) & 63;
    int n  = bid >> 10;
    int m0 = mt * 64;
    int b  = m0 >> 7;
    int f0 = m0 & 127;
    int j0 = jt * 64;
    int t = threadIdx.x;
    int tr = t >> 4, tc = t & 15;
    __shared__ float xs[16][65];
    __shared__ float wt[16][65];
    float acc[4][4] = {};
    const float* xb = x + (size_t)b * 1048576 + (size_t)f0 * 16 + n;
    const float* Wn = W + (size_t)n * 524288 + j0;
    for (int c0 = 0; c0 < 512; c0 += 16) {
#pragma unroll
        for (int i = 0; i < 4; ++i) {
            int v  = i * 256 + t;
            int ci = v >> 6, e = v & 63;
            xs[ci][e] = xb[(size_t)(c0 + ci) * 2048 + (size_t)e * 16];
            wt[ci][e] = Wn[(size_t)(c0 + ci) * 1024 + e];
        }
        __syncthreads();
#pragma unroll
        for (int c = 0; c < 16; ++c) {
            float a0 = xs[c][tr * 4], a1 = xs[c][tr * 4 + 1],
                  a2 = xs[c][tr * 4 + 2], a3 = xs[c][tr * 4 + 3];
            float w0 = wt[c][tc * 4], w1 = wt[c][tc * 4 + 1],
                  w2 = wt[c][tc * 4 + 2], w3 = wt[c][tc * 4 + 3];
            acc[0][0] = fmaf(a0, w0, acc[0][0]); acc[0][1] = fmaf(a0, w1, acc[0][1]);
            acc[0][2] = fmaf(a0, w2, acc[0][2]); acc[0][3] = fmaf(a0, w3, acc[0][3]);
            acc[1][0] = fmaf(a1, w0, acc[1][0]); acc[1][1] = fmaf(a1, w1, acc[1][1]);
            acc[1][2] = fmaf(a1, w2, acc[1][2]); acc[1][3] = fmaf(a1, w3, acc[1][3]);
            acc[2][0] = fmaf(a2, w0, acc[2][0]); acc[2][1] = fmaf(a2, w1, acc[2][1]);
            acc[2][2] = fmaf(a2, w2, acc[2][2]); acc[2][3] = fmaf(a2, w3, acc[2][3]);
            acc[3][0] = fmaf(a3, w0, acc[3][0]); acc[3][1] = fmaf(a3, w1, acc[3][1]);
            acc[3][2] = fmaf(a3, w2, acc[3][2]); acc[3][3] = fmaf(a3, w3, acc[3][3]);
        }
        __syncthreads();
    }
#pragma unroll
    for (int r = 0; r < 4; ++r) {
        int f = f0 + tr * 4 + r;
#pragma unroll
        for (int q = 0; q < 4; ++q) {
            int j = j0 + tc * 4 + q;
            int o = j >> 1, k = j & 1;
            out[(size_t)b * 2097152 + (size_t)o * 4096 + (size_t)f * 32 + n * 2 + k] =
                acc[r][q] + bias[n * 512 + o];
        }
    }
}

extern "C" void kernel_launch(void* const* d_in, const int* in_sizes, int n_in,
                              void* d_out, int out_size, void* d_ws, size_t ws_size,
                              hipStream_t stream) {
    (void)in_sizes; (void)n_in; (void)out_size;
    const float* x    = (const float*)d_in[0];
    const float* W    = (const float*)d_in[1];
    const float* bias = (const float*)d_in[2];
    float* out = (float*)d_out;

    const size_t xT_bytes = 67108864;    // 16*4096*512 bf16
    const size_t Wb_bytes = 16777216;    // 16*1024*512 bf16
    const size_t Y_bytes  = 134217728;   // 16*4096*1024 bf16
    const size_t need = xT_bytes + Wb_bytes + Y_bytes;   // 208 MB

    if (ws_size >= need) {
        u16* xT  = (u16*)d_ws;
        u16* WbT = (u16*)((char*)d_ws + xT_bytes);
        u16* Y   = (u16*)((char*)d_ws + xT_bytes + Wb_bytes);
        k_transpose_x<<<dim3(2048), dim3(256), 0, stream>>>(x, xT);
        k_transpose_w<<<dim3(512), dim3(256), 0, stream>>>(W, WbT);
        k_gemm<<<dim3(4096), dim3(256), 0, stream>>>(xT, WbT, bias, Y);
        k_reassemble<<<dim3(8192), dim3(256), 0, stream>>>(Y, out);
    } else {
        k_fallback<<<dim3(16384), dim3(256), 0, stream>>>(x, W, bias, out);
    }
}